// Round 2
// baseline (802.348 us; speedup 1.0000x reference)
//
#include <hip/hip_runtime.h>

#define Bsz 256
#define Tsz 512
#define Isz 64
#define Hsz 128
#define G4  512   // 4*H

typedef _Float16 f16;
typedef _Float16 f16x8 __attribute__((ext_vector_type(8)));
typedef _Float16 f16x4 __attribute__((ext_vector_type(4)));
typedef float floatx4 __attribute__((ext_vector_type(4)));

#define MFMA(A, B, C) __builtin_amdgcn_mfma_f32_16x16x32_f16((A), (B), (C), 0, 0, 0)

// LDS-only barrier: drains lgkmcnt but NOT vmcnt -> in-loop global traffic
// (prefetch loads, hs stores) never serializes a step.
__device__ __forceinline__ void lds_barrier() {
  asm volatile("s_waitcnt lgkmcnt(0)\n\ts_barrier" ::: "memory");
}

__device__ __forceinline__ float sigm_f(float x) {
  float e = __builtin_amdgcn_exp2f(x * -1.4426950408889634f);
  return __builtin_amdgcn_rcpf(1.0f + e);
}
__device__ __forceinline__ float tanh_f(float x) {
  float e = __builtin_amdgcn_exp2f(x * -2.8853900817779268f);
  return 2.0f * __builtin_amdgcn_rcpf(1.0f + e) - 1.0f;
}

__global__ void cvt_f32_f16(const float* __restrict__ in, f16* __restrict__ out, int n4) {
  int i = blockIdx.x * blockDim.x + threadIdx.x;
  if (i < n4) {
    float4 v = ((const float4*)in)[i];
    f16x4 o;
    o[0] = (f16)v.x; o[1] = (f16)v.y; o[2] = (f16)v.z; o[3] = (f16)v.w;
    ((f16x4*)out)[i] = o;
  }
}

__device__ __forceinline__ f16x8 load_wfrag(const float* __restrict__ W, int n, int stride, int k) {
  const float* p = W + (size_t)n * stride + k;
  float4 a = *(const float4*)p;
  float4 b = *(const float4*)(p + 4);
  f16x8 r;
  r[0] = (f16)a.x; r[1] = (f16)a.y; r[2] = (f16)a.z; r[3] = (f16)a.w;
  r[4] = (f16)b.x; r[5] = (f16)b.y; r[6] = (f16)b.z; r[7] = (f16)b.w;
  return r;
}

// Shared-denominator LSTM cell: 5 exp2 + 2 rcp.
__device__ __forceinline__ float lstm_cell(float ipre, float fpre, float gpre,
                                           float opre, float& c) {
  const float ei = __builtin_amdgcn_exp2f(fminf(ipre * -1.4426950408889634f, 30.f));
  const float ef = __builtin_amdgcn_exp2f(fminf(fpre * -1.4426950408889634f, 30.f));
  const float eg = __builtin_amdgcn_exp2f(fminf(gpre * -2.8853900817779268f, 30.f));
  const float eo = __builtin_amdgcn_exp2f(fminf(opre * -1.4426950408889634f, 30.f));
  const float pf1 = 1.f + ef;
  const float P = (1.f + ei) * (1.f + eg);
  const float num = fmaf(c, P, pf1 * (1.f - eg));
  const float cn = num * __builtin_amdgcn_rcpf(pf1 * P);
  c = cn;
  const float ec = __builtin_amdgcn_exp2f(fminf(cn * -2.8853900817779268f, 30.f));
  return (1.f - ec) * __builtin_amdgcn_rcpf((1.f + eo) * (1.f + ec));
}

// Layer-0 BiLSTM scan, 2 batches/block, 1 cell/lane, 4 waves (256 thr) ->
// exactly 1 wave/SIMD: no intra-SIMD issue contention inside the per-step
// barrier interval, 4-wave barrier skew. 256 blocks (0..127 fwd, 128..255
// rev). Batch is packed into A-row parity (A[row] = h[(row>>2)&1]) so every
// lane extracts its gates from accumulator REG 0 (1 cndmask per gate).
// hq stride 160 f16: reads hit all 32 banks, 8-way broadcast, conflict-free.
// Depth-2 x-prefetch ring (load->use = 2 steps), no per-step vmcnt drain.
__global__ __launch_bounds__(256, 1) void lstm_scan_l0(
    const f16* __restrict__ xf,
    const float* __restrict__ Wih_f, const float* __restrict__ Whh_f,
    const float* __restrict__ bih_f, const float* __restrict__ bhh_f,
    const float* __restrict__ Wih_r, const float* __restrict__ Whh_r,
    const float* __restrict__ bih_r, const float* __restrict__ bhh_r,
    f16* __restrict__ hs) {
  const int dir = ((int)blockIdx.x >= 128) ? 1 : 0;
  const int bb = ((int)blockIdx.x & 127) * 2;
  const float* __restrict__ Wih = dir ? Wih_r : Wih_f;
  const float* __restrict__ Whh = dir ? Whh_r : Whh_f;
  const float* __restrict__ bih = dir ? bih_r : bih_f;
  const float* __restrict__ bhh = dir ? bhh_r : bhh_f;

  __shared__ __align__(16) f16 hq[2][2][160];

  const int tid = threadIdx.x;
  const int lane = tid & 63;
  const int w = tid >> 6;              // 0..3 (wave)
  const int l15 = lane & 15;
  const int q = lane >> 4;             // 0..3
  const bool qb1 = (q & 2) != 0;       // col-tile select
  const int mybat = q & 1;             // this lane's batch (0/1)
  const int abat = (l15 >> 2) & 1;     // batch replicated into this lane's A rows
  const int mycol = w * 32 + (qb1 ? 16 : 0) + l15;

  // B-fragments: wave w owns cols [w*32, w*32+32) = 2 col-tiles x 4 gates.
  f16x8 wi[4][2][2], wh[4][2][4];
  float bsum[4][2];
#pragma unroll
  for (int g = 0; g < 4; ++g)
#pragma unroll
    for (int ct = 0; ct < 2; ++ct) {
      const int n = g * 128 + w * 32 + ct * 16 + l15;
#pragma unroll
      for (int kt = 0; kt < 2; ++kt) wi[g][ct][kt] = load_wfrag(Wih, n, Isz, kt * 32 + q * 8);
#pragma unroll
      for (int kt = 0; kt < 4; ++kt) wh[g][ct][kt] = load_wfrag(Whh, n, Hsz, kt * 32 + q * 8);
      bsum[g][ct] = bih[n] + bhh[n];
    }

  for (int i = tid; i < 2 * 2 * 160; i += 256) (&hq[0][0][0])[i] = (f16)0.f;

  float cst = 0.f;
  const int t0 = dir ? (Tsz - 1) : 0;
  const int dt = dir ? -1 : 1;
  const ptrdiff_t xstep = (ptrdiff_t)dt * Isz;

  const f16* xp = xf + ((size_t)(bb + abat) * Tsz + t0) * Isz + q * 8;

  // prime gacc = bias + xproj(t0)
  floatx4 gacc[4][2];
  {
    f16x8 x0 = *(const f16x8*)xp;
    f16x8 x1 = *(const f16x8*)(xp + 32);
#pragma unroll
    for (int g = 0; g < 4; ++g)
#pragma unroll
      for (int ct = 0; ct < 2; ++ct) {
        floatx4 a;
        const float b = bsum[g][ct];
        a[0] = b; a[1] = b; a[2] = b; a[3] = b;
        a = MFMA(x0, wi[g][ct][0], a);
        a = MFMA(x1, wi[g][ct][1], a);
        gacc[g][ct] = a;
      }
  }

  // ring slot s holds x(t+1) for steps t == s (mod 2); primed with x(1..2)
  f16x8 r0a = *(const f16x8*)(xp + 1 * xstep), r0b = *(const f16x8*)(xp + 1 * xstep + 32);
  f16x8 r1a = *(const f16x8*)(xp + 2 * xstep), r1b = *(const f16x8*)(xp + 2 * xstep + 32);
  const f16* xpn = xp + 3 * xstep;   // next address to load: x(t+3) at step t

  f16* hsp = hs + ((size_t)(bb + mybat) * Tsz + t0) * 256 + dir * 128 + mycol;
  const ptrdiff_t hstep = (ptrdiff_t)dt * 256;

  __syncthreads();

  auto step = [&](int t, f16x8& ra, f16x8& rb) {
    f16x8 ah[4];
#pragma unroll
    for (int kt = 0; kt < 4; ++kt)
      ah[kt] = *(const f16x8*)(&hq[t & 1][abat][kt * 32 + q * 8]);
#pragma unroll
    for (int kt = 0; kt < 4; ++kt)
#pragma unroll
      for (int g = 0; g < 4; ++g)
#pragma unroll
        for (int ct = 0; ct < 2; ++ct)
          gacc[g][ct] = MFMA(ah[kt], wh[g][ct][kt], gacc[g][ct]);

    // C rows 4q..4q+3 all carry batch (q&1); reg 0 is this lane's cell.
    const float ipre = qb1 ? gacc[0][1][0] : gacc[0][0][0];
    const float fpre = qb1 ? gacc[1][1][0] : gacc[1][0][0];
    const float gpre = qb1 ? gacc[2][1][0] : gacc[2][0][0];
    const float opre = qb1 ? gacc[3][1][0] : gacc[3][0][0];
    const float h = lstm_cell(ipre, fpre, gpre, opre, cst);
    const f16 hf = (f16)h;
    hq[(t + 1) & 1][mybat][mycol] = hf;
    *hsp = hf;
    hsp += hstep;

    if (t + 1 < Tsz) {
      // xproj for t+1 from this body's ring slot (loaded 2 steps ago)
#pragma unroll
      for (int g = 0; g < 4; ++g)
#pragma unroll
        for (int ct = 0; ct < 2; ++ct) {
          floatx4 na;
          const float b = bsum[g][ct];
          na[0] = b; na[1] = b; na[2] = b; na[3] = b;
          na = MFMA(ra, wi[g][ct][0], na);
          na = MFMA(rb, wi[g][ct][1], na);
          gacc[g][ct] = na;
        }
      // refill this slot with x(t+3), consumed at step t+2
      if (t + 3 < Tsz) {
        ra = *(const f16x8*)xpn;
        rb = *(const f16x8*)(xpn + 32);
        xpn += xstep;
      }
    }
    lds_barrier();
  };

  for (int tb = 0; tb < Tsz; tb += 2) {
    step(tb + 0, r0a, r0b);
    step(tb + 1, r1a, r1b);
  }
}

// xg GEMM for layer-1 fwd. Output layout: xg[b][t][col][g] f16x4 (biases
// folded) so each scan lane reads its cell's 4 gate-pre values as one 8B
// load. Grid 256 = 16 batch-groups x 16 t-chunks of 32.
__global__ __launch_bounds__(512, 1) void xg_gemm_l1(
    const f16* __restrict__ hs, const float* __restrict__ Wih,
    const float* __restrict__ bih, const float* __restrict__ bhh,
    f16* __restrict__ xg) {
  const int bg = (int)blockIdx.x & 15;
  const int tc = (int)blockIdx.x >> 4;
  const int bb = bg * 16;

  const int tid = threadIdx.x;
  const int lane = tid & 63;
  const int w = tid >> 6;
  const int l15 = lane & 15;
  const int q = lane >> 4;
  const int jcol = w * 16 + l15;

  f16x8 wi[4][8];
  float bsum[4];
#pragma unroll
  for (int g = 0; g < 4; ++g) {
    const int n = g * 128 + jcol;
#pragma unroll
    for (int kt = 0; kt < 8; ++kt) wi[g][kt] = load_wfrag(Wih, n, 256, kt * 32 + q * 8);
    bsum[g] = bih[n] + bhh[n];
  }

  const f16* ap = hs + ((size_t)(bb + l15) * Tsz + tc * 32) * 256 + q * 8;
  // lane holds acc[g][r] for batch bb+4q+r, col jcol
  f16* op = xg + (((size_t)(bb + 4 * q) * Tsz + tc * 32) * 128 + jcol) * 4;
  const size_t rstride = (size_t)Tsz * 512;   // f16 units per batch row

  for (int tt = 0; tt < 32; ++tt) {
    f16x8 a[8];
#pragma unroll
    for (int kt = 0; kt < 8; ++kt) a[kt] = *(const f16x8*)(ap + kt * 32);
    ap += 256;

    floatx4 acc[4];
#pragma unroll
    for (int g = 0; g < 4; ++g) {
      acc[g][0] = bsum[g]; acc[g][1] = bsum[g];
      acc[g][2] = bsum[g]; acc[g][3] = bsum[g];
    }
#pragma unroll
    for (int kt = 0; kt < 8; ++kt)
#pragma unroll
      for (int g = 0; g < 4; ++g) acc[g] = MFMA(a[kt], wi[g][kt], acc[g]);

#pragma unroll
    for (int r = 0; r < 4; ++r) {
      f16x4 o;
      o[0] = (f16)acc[0][r]; o[1] = (f16)acc[1][r];
      o[2] = (f16)acc[2][r]; o[3] = (f16)acc[3][r];
      *(f16x4*)(op + (size_t)r * rstride) = o;
    }
    op += 512;
  }
}

// Layer-1 forward scan from precomputed xg. 128 blocks x 2 batches, 1 cell/
// lane, 4 waves (1 wave/SIMD). Depth-4 xg prefetch ring (2 x f16x4 per slot:
// both col-tiles of the lane's batch). LDS-only barrier.
__global__ __launch_bounds__(256, 1) void lstm_scan_l1x(
    const f16* __restrict__ xg, const float* __restrict__ Whh,
    float* __restrict__ hfinal) {
  const int bb = (int)blockIdx.x * 2;

  __shared__ __align__(16) f16 hq[2][2][160];

  const int tid = threadIdx.x;
  const int lane = tid & 63;
  const int w = tid >> 6;
  const int l15 = lane & 15;
  const int q = lane >> 4;
  const bool qb1 = (q & 2) != 0;
  const int mybat = q & 1;
  const int abat = (l15 >> 2) & 1;
  const int mycol = w * 32 + (qb1 ? 16 : 0) + l15;

  f16x8 wh[4][2][4];
#pragma unroll
  for (int g = 0; g < 4; ++g)
#pragma unroll
    for (int ct = 0; ct < 2; ++ct) {
      const int n = g * 128 + w * 32 + ct * 16 + l15;
#pragma unroll
      for (int kt = 0; kt < 4; ++kt) wh[g][ct][kt] = load_wfrag(Whh, n, Hsz, kt * 32 + q * 8);
    }

  for (int i = tid; i < 2 * 2 * 160; i += 256) (&hq[0][0][0])[i] = (f16)0.f;

  float cst = 0.f;

  // per step the lane needs xg for BOTH its wave's col-tiles (batch q&1):
  // cols w*32+l15 and w*32+16+l15 -> two f16x4 at +0 / +64 f16.
  const f16* gp = xg + (size_t)(bb + mybat) * Tsz * 512 + (w * 32 + l15) * 4;
  // ring slot s = xg(t) for t == s (mod 4); primed with xg(0..3)
  f16x4 s0a = *(const f16x4*)gp,            s0b = *(const f16x4*)(gp + 64);
  f16x4 s1a = *(const f16x4*)(gp + 512),    s1b = *(const f16x4*)(gp + 576);
  f16x4 s2a = *(const f16x4*)(gp + 1024),   s2b = *(const f16x4*)(gp + 1088);
  f16x4 s3a = *(const f16x4*)(gp + 1536),   s3b = *(const f16x4*)(gp + 1600);
  const f16* gpn = gp + 2048;   // next load: xg(t+4) at step t

  __syncthreads();

  auto step = [&](int t, f16x4& sa, f16x4& sb) {
    f16x8 ah[4];
#pragma unroll
    for (int kt = 0; kt < 4; ++kt)
      ah[kt] = *(const f16x8*)(&hq[t & 1][abat][kt * 32 + q * 8]);

    floatx4 gacc[4][2];
#pragma unroll
    for (int g = 0; g < 4; ++g) {
      const float v0 = (float)sa[g];
      const float v1 = (float)sb[g];
      gacc[g][0][0] = v0; gacc[g][0][1] = v0; gacc[g][0][2] = v0; gacc[g][0][3] = v0;
      gacc[g][1][0] = v1; gacc[g][1][1] = v1; gacc[g][1][2] = v1; gacc[g][1][3] = v1;
    }
#pragma unroll
    for (int kt = 0; kt < 4; ++kt)
#pragma unroll
      for (int g = 0; g < 4; ++g)
#pragma unroll
        for (int ct = 0; ct < 2; ++ct)
          gacc[g][ct] = MFMA(ah[kt], wh[g][ct][kt], gacc[g][ct]);

    const float ipre = qb1 ? gacc[0][1][0] : gacc[0][0][0];
    const float fpre = qb1 ? gacc[1][1][0] : gacc[1][0][0];
    const float gpre = qb1 ? gacc[2][1][0] : gacc[2][0][0];
    const float opre = qb1 ? gacc[3][1][0] : gacc[3][0][0];
    const float h = lstm_cell(ipre, fpre, gpre, opre, cst);
    hq[(t + 1) & 1][mybat][mycol] = (f16)h;
    if (t == Tsz - 1)
      hfinal[(size_t)(bb + mybat) * Hsz + mycol] = h;

    // refill this slot with xg(t+4)
    if (t + 4 < Tsz) {
      sa = *(const f16x4*)gpn;
      sb = *(const f16x4*)(gpn + 64);
      gpn += 512;
    }
    lds_barrier();
  };

  for (int tb = 0; tb < Tsz; tb += 4) {
    step(tb + 0, s0a, s0b);
    step(tb + 1, s1a, s1b);
    step(tb + 2, s2a, s2b);
    step(tb + 3, s3a, s3b);
  }
}

// Fallback layer-1 scan (reads hs directly) for small ws. 16 blocks.
__global__ __launch_bounds__(512, 1) void lstm_scan_l1_fb(
    const f16* __restrict__ hs,
    const float* __restrict__ Wih, const float* __restrict__ Whh,
    const float* __restrict__ bih, const float* __restrict__ bhh,
    float* __restrict__ hfinal) {
  const int bb = (int)blockIdx.x * 16;
  __shared__ __align__(16) f16 hq[2][16][136];
  __shared__ __align__(16) f16 xq[2][16][264];

  const int tid = threadIdx.x;
  const int lane = tid & 63;
  const int w = tid >> 6;
  const int l15 = lane & 15;
  const int q = lane >> 4;
  const int jcol = w * 16 + l15;

  f16x8 wi[4][8], wh[4][4];
  float bsum[4];
#pragma unroll
  for (int g = 0; g < 4; ++g) {
    const int n = g * 128 + jcol;
#pragma unroll
    for (int kt = 0; kt < 8; ++kt) wi[g][kt] = load_wfrag(Wih, n, 256, kt * 32 + q * 8);
#pragma unroll
    for (int kt = 0; kt < 4; ++kt) wh[g][kt] = load_wfrag(Whh, n, Hsz, kt * 32 + q * 8);
    bsum[g] = bih[n] + bhh[n];
  }
  for (int i = tid; i < 2 * 16 * 136; i += 512) (&hq[0][0][0])[i] = (f16)0.f;
  float cst[4] = {0.f, 0.f, 0.f, 0.f};

  floatx4 gacc[4];
  {
    const f16* pp = hs + (size_t)(bb + l15) * Tsz * 256 + q * 8;
#pragma unroll
    for (int g = 0; g < 4; ++g) {
      gacc[g][0] = bsum[g]; gacc[g][1] = bsum[g];
      gacc[g][2] = bsum[g]; gacc[g][3] = bsum[g];
    }
#pragma unroll
    for (int kt = 0; kt < 8; ++kt) {
      f16x8 xa = *(const f16x8*)(pp + kt * 32);
#pragma unroll
      for (int g = 0; g < 4; ++g) gacc[g] = MFMA(xa, wi[g][kt], gacc[g]);
    }
  }
  const int sm = tid >> 5;
  const int sc = tid & 31;
  const f16* spg = hs + (size_t)(bb + sm) * Tsz * 256 + sc * 8;
  const f16* spn = spg + 3 * 256;
  f16x8 ld;
  *(f16x8*)(&xq[1][sm][sc * 8]) = *(const f16x8*)(spg + 256);
  ld = *(const f16x8*)(spg + 2 * 256);
  __syncthreads();

  for (int t = 0; t < Tsz; ++t) {
    f16x8 xa[8];
    if (t + 1 < Tsz) {
      const f16* xrow = &xq[(t + 1) & 1][l15][0];
#pragma unroll
      for (int kt = 0; kt < 8; ++kt) xa[kt] = *(const f16x8*)(xrow + kt * 32 + q * 8);
    }
    f16x8 ah[4];
#pragma unroll
    for (int kt = 0; kt < 4; ++kt)
      ah[kt] = *(const f16x8*)(&hq[t & 1][l15][kt * 32 + q * 8]);
#pragma unroll
    for (int kt = 0; kt < 4; ++kt)
#pragma unroll
      for (int g = 0; g < 4; ++g) gacc[g] = MFMA(ah[kt], wh[g][kt], gacc[g]);

#pragma unroll
    for (int r = 0; r < 4; ++r) {
      const float h = lstm_cell(gacc[0][r], gacc[1][r], gacc[2][r], gacc[3][r], cst[r]);
      hq[(t + 1) & 1][4 * q + r][jcol] = (f16)h;
      if (t == Tsz - 1) hfinal[(size_t)(bb + 4 * q + r) * Hsz + jcol] = h;
    }
    if (t + 2 < Tsz) *(f16x8*)(&xq[t & 1][sm][sc * 8]) = ld;
    if (t + 3 < Tsz) { ld = *(const f16x8*)spn; spn += 256; }
    if (t + 1 < Tsz) {
      floatx4 nacc[4];
#pragma unroll
      for (int g = 0; g < 4; ++g) {
        nacc[g][0] = bsum[g]; nacc[g][1] = bsum[g];
        nacc[g][2] = bsum[g]; nacc[g][3] = bsum[g];
      }
#pragma unroll
      for (int kt = 0; kt < 8; ++kt)
#pragma unroll
        for (int g = 0; g < 4; ++g) nacc[g] = MFMA(xa[kt], wi[g][kt], nacc[g]);
#pragma unroll
      for (int g = 0; g < 4; ++g) gacc[g] = nacc[g];
    }
    lds_barrier();
  }
}

// L1-reverse single step (h0=c0=0) + FC head. 1 block/batch.
__global__ __launch_bounds__(512) void tail_kernel(
    const f16* __restrict__ hs, const float* __restrict__ hfinal,
    const float* __restrict__ Wr, const float* __restrict__ br1,
    const float* __restrict__ br2, const float* __restrict__ fc1w,
    const float* __restrict__ fc1b, const float* __restrict__ fc2w,
    const float* __restrict__ fc2b, float* __restrict__ out) {
  const int b = blockIdx.x;
  const int tid = threadIdx.x;
  __shared__ float hrow[256];
  __shared__ float gact[512];
  __shared__ float last[256];
  __shared__ float hid[128];
  __shared__ float psum[128];

  const size_t row = ((size_t)b * Tsz + (Tsz - 1)) * 256;
  if (tid < 256) hrow[tid] = (float)hs[row + tid];
  __syncthreads();

  {
    float a = br1[tid] + br2[tid];
    const float* wr = Wr + (size_t)tid * 256;
#pragma unroll 8
    for (int k = 0; k < 256; ++k) a += hrow[k] * wr[k];
    gact[tid] = (tid >= 256 && tid < 384) ? tanh_f(a) : sigm_f(a);
  }
  __syncthreads();

  if (tid < 128) {
    const float c = gact[tid] * gact[256 + tid];
    const float hb = gact[384 + tid] * tanh_f(c);
    last[tid] = hfinal[(size_t)b * Hsz + tid];
    last[128 + tid] = hb;
  }
  __syncthreads();

  if (tid < 128) {
    float a = fc1b[tid];
    const float* w1 = fc1w + (size_t)tid * 256;
#pragma unroll 8
    for (int k = 0; k < 256; ++k) a += last[k] * w1[k];
    hid[tid] = fmaxf(a, 0.f);
  }
  __syncthreads();
  if (tid < 128) psum[tid] = hid[tid] * fc2w[tid];
  __syncthreads();
  if (tid == 0) {
    float s = fc2b[0];
    for (int k = 0; k < 128; ++k) s += psum[k];
    out[b] = s;
  }
}

extern "C" void kernel_launch(void* const* d_in, const int* in_sizes, int n_in,
                              void* d_out, int out_size, void* d_ws, size_t ws_size,
                              hipStream_t stream) {
  (void)in_sizes; (void)n_in; (void)out_size;
  const float* x = (const float*)d_in[0];
  const float* Wih_l0 = (const float*)d_in[1];
  const float* Whh_l0 = (const float*)d_in[2];
  const float* bih_l0 = (const float*)d_in[3];
  const float* bhh_l0 = (const float*)d_in[4];
  const float* Wih_l0r = (const float*)d_in[5];
  const float* Whh_l0r = (const float*)d_in[6];
  const float* bih_l0r = (const float*)d_in[7];
  const float* bhh_l0r = (const float*)d_in[8];
  const float* Wih_l1 = (const float*)d_in[9];
  const float* Whh_l1 = (const float*)d_in[10];
  const float* bih_l1 = (const float*)d_in[11];
  const float* bhh_l1 = (const float*)d_in[12];
  const float* Wih_l1r = (const float*)d_in[13];
  // d_in[14] = W_hh_l1r unused (reverse h0 = 0)
  const float* bih_l1r = (const float*)d_in[15];
  const float* bhh_l1r = (const float*)d_in[16];
  const float* fc1w = (const float*)d_in[17];
  const float* fc1b = (const float*)d_in[18];
  const float* fc2w = (const float*)d_in[19];
  const float* fc2b = (const float*)d_in[20];
  float* out = (float*)d_out;

  char* ws = (char*)d_ws;
  const size_t M = (size_t)Bsz * Tsz;        // 131072
  const size_t XFB = M * Isz * 2;            // 16.8 MB  x in f16
  const size_t HSB = M * 256 * 2;            // 67.1 MB  hs in f16
  const size_t HFB = (size_t)Bsz * Hsz * 4;  // 131 KB   L1 fwd final h
  const size_t XGB = M * 512 * 2;            // 134 MB   l1 xg f16 [b][t][col][g]
  const size_t need_min = XFB + HSB + HFB;
  const size_t need_full = need_min + XGB;
  if (ws_size < need_min) return;
  const bool fast = ws_size >= need_full;

  size_t off = 0;
  f16* xf = (f16*)(ws + off); off += XFB;
  f16* hsb = (f16*)(ws + off); off += HSB;
  float* hfinal = (float*)(ws + off); off += HFB;
  f16* xgb = fast ? (f16*)(ws + off) : nullptr;

  const int n4 = (int)(M * Isz / 4);
  cvt_f32_f16<<<dim3((n4 + 255) / 256), dim3(256), 0, stream>>>(x, xf, n4);

  lstm_scan_l0<<<dim3(256), dim3(256), 0, stream>>>(
      xf, Wih_l0, Whh_l0, bih_l0, bhh_l0, Wih_l0r, Whh_l0r, bih_l0r, bhh_l0r, hsb);

  if (fast) {
    xg_gemm_l1<<<dim3(256), dim3(512), 0, stream>>>(hsb, Wih_l1, bih_l1, bhh_l1, xgb);
    lstm_scan_l1x<<<dim3(128), dim3(256), 0, stream>>>(xgb, Whh_l1, hfinal);
  } else {
    lstm_scan_l1_fb<<<dim3(16), dim3(512), 0, stream>>>(
        hsb, Wih_l1, Whh_l1, bih_l1, bhh_l1, hfinal);
  }

  tail_kernel<<<dim3(256), dim3(512), 0, stream>>>(
      hsb, hfinal, Wih_l1r, bih_l1r, bhh_l1r, fc1w, fc1b, fc2w, fc2b, out);
}

// Round 3
// 801.756 us; speedup vs baseline: 1.0007x; 1.0007x over previous
//
#include <hip/hip_runtime.h>

#define Bsz 256
#define Tsz 512
#define Isz 64
#define Hsz 128
#define G4  512   // 4*H

typedef _Float16 f16;
typedef _Float16 f16x8 __attribute__((ext_vector_type(8)));
typedef _Float16 f16x4 __attribute__((ext_vector_type(4)));
typedef float floatx4 __attribute__((ext_vector_type(4)));

#define MFMA(A, B, C) __builtin_amdgcn_mfma_f32_16x16x32_f16((A), (B), (C), 0, 0, 0)

// LDS-only barrier: drains lgkmcnt but NOT vmcnt -> in-loop global traffic
// (prefetch loads, hs stores) never serializes a step.
__device__ __forceinline__ void lds_barrier() {
  asm volatile("s_waitcnt lgkmcnt(0)\n\ts_barrier" ::: "memory");
}

__device__ __forceinline__ float sigm_f(float x) {
  float e = __builtin_amdgcn_exp2f(x * -1.4426950408889634f);
  return __builtin_amdgcn_rcpf(1.0f + e);
}
__device__ __forceinline__ float tanh_f(float x) {
  float e = __builtin_amdgcn_exp2f(x * -2.8853900817779268f);
  return 2.0f * __builtin_amdgcn_rcpf(1.0f + e) - 1.0f;
}

__global__ void cvt_f32_f16(const float* __restrict__ in, f16* __restrict__ out, int n4) {
  int i = blockIdx.x * blockDim.x + threadIdx.x;
  if (i < n4) {
    float4 v = ((const float4*)in)[i];
    f16x4 o;
    o[0] = (f16)v.x; o[1] = (f16)v.y; o[2] = (f16)v.z; o[3] = (f16)v.w;
    ((f16x4*)out)[i] = o;
  }
}

__device__ __forceinline__ f16x8 load_wfrag(const float* __restrict__ W, int n, int stride, int k) {
  const float* p = W + (size_t)n * stride + k;
  float4 a = *(const float4*)p;
  float4 b = *(const float4*)(p + 4);
  f16x8 r;
  r[0] = (f16)a.x; r[1] = (f16)a.y; r[2] = (f16)a.z; r[3] = (f16)a.w;
  r[4] = (f16)b.x; r[5] = (f16)b.y; r[6] = (f16)b.z; r[7] = (f16)b.w;
  return r;
}

// Shared-denominator LSTM cell: 5 exp2 + 2 rcp.
__device__ __forceinline__ float lstm_cell(float ipre, float fpre, float gpre,
                                           float opre, float& c) {
  const float ei = __builtin_amdgcn_exp2f(fminf(ipre * -1.4426950408889634f, 30.f));
  const float ef = __builtin_amdgcn_exp2f(fminf(fpre * -1.4426950408889634f, 30.f));
  const float eg = __builtin_amdgcn_exp2f(fminf(gpre * -2.8853900817779268f, 30.f));
  const float eo = __builtin_amdgcn_exp2f(fminf(opre * -1.4426950408889634f, 30.f));
  const float pf1 = 1.f + ef;
  const float P = (1.f + ei) * (1.f + eg);
  const float num = fmaf(c, P, pf1 * (1.f - eg));
  const float cn = num * __builtin_amdgcn_rcpf(pf1 * P);
  c = cn;
  const float ec = __builtin_amdgcn_exp2f(fminf(cn * -2.8853900817779268f, 30.f));
  return (1.f - ec) * __builtin_amdgcn_rcpf((1.f + eo) * (1.f + ec));
}

// ---------------------------------------------------------------------------
// NEW FAST PATH: xg precomputed for BOTH layers -> scans are pure-recurrent
// (32 MFMA/SIMD/step = the 16x16x32 packing floor, ~620 cy) instead of 48.
// ---------------------------------------------------------------------------

// xg GEMM for layer 0 (both dirs). Reads x in f32 (cvt fused), folds biases.
// Output xg0[dir][b][t][col][g] f16x4 per (col): scan lane reads ONE 8B load
// per step. Grid 512 = 2 dirs x 16 batch-groups x 16 t-chunks of 32.
__global__ __launch_bounds__(512, 1) void xg_gemm_l0(
    const float* __restrict__ x,
    const float* __restrict__ Wih_f, const float* __restrict__ bih_f,
    const float* __restrict__ bhh_f,
    const float* __restrict__ Wih_r, const float* __restrict__ bih_r,
    const float* __restrict__ bhh_r,
    f16* __restrict__ xg0) {
  const int blk = (int)blockIdx.x;
  const int dir = blk >> 8;
  const int bg = blk & 15;
  const int tc = (blk >> 4) & 15;
  const int bb = bg * 16;
  const float* __restrict__ Wih = dir ? Wih_r : Wih_f;
  const float* __restrict__ bih = dir ? bih_r : bih_f;
  const float* __restrict__ bhh = dir ? bhh_r : bhh_f;

  const int tid = threadIdx.x;
  const int lane = tid & 63;
  const int w = tid >> 6;
  const int l15 = lane & 15;
  const int q = lane >> 4;
  const int jcol = w * 16 + l15;

  f16x8 wi[4][2];
  floatx4 bvec[4];
#pragma unroll
  for (int g = 0; g < 4; ++g) {
    const int n = g * 128 + jcol;
#pragma unroll
    for (int kt = 0; kt < 2; ++kt) wi[g][kt] = load_wfrag(Wih, n, Isz, kt * 32 + q * 8);
    const float b = bih[n] + bhh[n];
    bvec[g][0] = b; bvec[g][1] = b; bvec[g][2] = b; bvec[g][3] = b;
  }

  const float* ap = x + ((size_t)(bb + l15) * Tsz + tc * 32) * Isz + q * 8;
  // lane holds acc[g][r] for batch bb+4q+r, col jcol
  f16* op = xg0 + (size_t)dir * ((size_t)Bsz * Tsz * 512)
          + (((size_t)(bb + 4 * q) * Tsz + tc * 32) * 128 + jcol) * 4;
  const size_t rstride = (size_t)Tsz * 512;

  for (int tt = 0; tt < 32; ++tt) {
    float4 a0 = *(const float4*)ap;
    float4 a1 = *(const float4*)(ap + 4);
    float4 b0 = *(const float4*)(ap + 32);
    float4 b1 = *(const float4*)(ap + 36);
    ap += Isz;
    f16x8 xa, xb;
    xa[0] = (f16)a0.x; xa[1] = (f16)a0.y; xa[2] = (f16)a0.z; xa[3] = (f16)a0.w;
    xa[4] = (f16)a1.x; xa[5] = (f16)a1.y; xa[6] = (f16)a1.z; xa[7] = (f16)a1.w;
    xb[0] = (f16)b0.x; xb[1] = (f16)b0.y; xb[2] = (f16)b0.z; xb[3] = (f16)b0.w;
    xb[4] = (f16)b1.x; xb[5] = (f16)b1.y; xb[6] = (f16)b1.z; xb[7] = (f16)b1.w;

    floatx4 acc[4];
#pragma unroll
    for (int g = 0; g < 4; ++g) {
      acc[g] = MFMA(xa, wi[g][0], bvec[g]);
      acc[g] = MFMA(xb, wi[g][1], acc[g]);
    }
#pragma unroll
    for (int r = 0; r < 4; ++r) {
      f16x4 o;
      o[0] = (f16)acc[0][r]; o[1] = (f16)acc[1][r];
      o[2] = (f16)acc[2][r]; o[3] = (f16)acc[3][r];
      *(f16x4*)(op + (size_t)r * rstride) = o;
    }
    op += 512;
  }
}

// Layer-0 BiLSTM scan from precomputed xg0. 128 blocks (0..63 fwd, 64..127
// rev) x 512 thr (8 waves, 2/SIMD for VALU<->MFMA overlap), 4 batches/block,
// 1 cell/lane. A-rows GROUPED by batch (row r = h[bat r>>2]) so lane q's 4
// C-regs are identical -> gate extraction = reg 0, zero cndmask; xg init =
// one f16x4 load broadcast. Per wave per step: 4 ds_read_b128 + 16 MFMA
// (pure K=128 recurrent) + cell. hq stride 144 (proven 0-conflict layout).
__global__ __launch_bounds__(512, 1) void lstm_scan_l0x(
    const f16* __restrict__ xg0,
    const float* __restrict__ Whh_f, const float* __restrict__ Whh_r,
    f16* __restrict__ hs) {
  const int dir = ((int)blockIdx.x >= 64) ? 1 : 0;
  const int bb = ((int)blockIdx.x & 63) * 4;
  const float* __restrict__ Whh = dir ? Whh_r : Whh_f;

  __shared__ __align__(16) f16 hq[2][4][144];

  const int tid = threadIdx.x;
  const int lane = tid & 63;
  const int w = tid >> 6;         // 0..7
  const int l15 = lane & 15;
  const int q = lane >> 4;        // k-slice AND this lane's batch
  const int jcol = w * 16 + l15;  // 0..127
  const int hrow = l15 >> 2;      // batch carried by this lane's A-row

  f16x8 wh[4][4];
#pragma unroll
  for (int g = 0; g < 4; ++g)
#pragma unroll
    for (int kt = 0; kt < 4; ++kt)
      wh[g][kt] = load_wfrag(Whh, g * 128 + jcol, Hsz, kt * 32 + q * 8);

  for (int i = tid; i < 2 * 4 * 144; i += 512) (&hq[0][0][0])[i] = (f16)0.f;

  float cst = 0.f;
  const int t0 = dir ? (Tsz - 1) : 0;
  const int dt = dir ? -1 : 1;

  const f16* gp = xg0 + (size_t)dir * ((size_t)Bsz * Tsz * 512)
                + ((size_t)(bb + q) * Tsz + t0) * 512 + jcol * 4;
  const ptrdiff_t gstep = (ptrdiff_t)dt * 512;

  // gacc primed with xg(step 0); ring s0=xg(1), s1=xg(2)
  floatx4 gacc[4];
  {
    f16x4 x0 = *(const f16x4*)gp;
#pragma unroll
    for (int g = 0; g < 4; ++g) {
      const float v = (float)x0[g];
      gacc[g][0] = v; gacc[g][1] = v; gacc[g][2] = v; gacc[g][3] = v;
    }
  }
  f16x4 s0 = *(const f16x4*)(gp + 1 * gstep);
  f16x4 s1 = *(const f16x4*)(gp + 2 * gstep);
  const f16* gpn = gp + 3 * gstep;

  f16* hsp = hs + ((size_t)(bb + q) * Tsz + t0) * 256 + dir * 128 + jcol;
  const ptrdiff_t hstep = (ptrdiff_t)dt * 256;

  __syncthreads();

  auto step = [&](int t, f16x4& sl) {
    f16x8 ah[4];
#pragma unroll
    for (int kt = 0; kt < 4; ++kt)
      ah[kt] = *(const f16x8*)(&hq[t & 1][hrow][kt * 32 + q * 8]);
#pragma unroll
    for (int kt = 0; kt < 4; ++kt)
#pragma unroll
      for (int g = 0; g < 4; ++g) gacc[g] = MFMA(ah[kt], wh[g][kt], gacc[g]);

    const float h = lstm_cell(gacc[0][0], gacc[1][0], gacc[2][0], gacc[3][0], cst);
    const f16 hf = (f16)h;
    hq[(t + 1) & 1][q][jcol] = hf;
    *hsp = hf;
    hsp += hstep;

    if (t + 1 < Tsz) {
      // refill gacc for t+1 from ring slot (loaded 2 steps ago)
#pragma unroll
      for (int g = 0; g < 4; ++g) {
        const float v = (float)sl[g];
        gacc[g][0] = v; gacc[g][1] = v; gacc[g][2] = v; gacc[g][3] = v;
      }
      if (t + 3 < Tsz) { sl = *(const f16x4*)gpn; gpn += gstep; }
    }
    lds_barrier();
  };

  for (int tb = 0; tb < Tsz; tb += 2) {
    step(tb + 0, s0);
    step(tb + 1, s1);
  }
}

// Layer-1 forward scan from precomputed xg1 (same structure, no dir, writes
// only final h). 64 blocks x 512 thr, 4 batches/block.
__global__ __launch_bounds__(512, 1) void lstm_scan_l1y(
    const f16* __restrict__ xg, const float* __restrict__ Whh,
    float* __restrict__ hfinal) {
  const int bb = (int)blockIdx.x * 4;

  __shared__ __align__(16) f16 hq[2][4][144];

  const int tid = threadIdx.x;
  const int lane = tid & 63;
  const int w = tid >> 6;
  const int l15 = lane & 15;
  const int q = lane >> 4;
  const int jcol = w * 16 + l15;
  const int hrow = l15 >> 2;

  f16x8 wh[4][4];
#pragma unroll
  for (int g = 0; g < 4; ++g)
#pragma unroll
    for (int kt = 0; kt < 4; ++kt)
      wh[g][kt] = load_wfrag(Whh, g * 128 + jcol, Hsz, kt * 32 + q * 8);

  for (int i = tid; i < 2 * 4 * 144; i += 512) (&hq[0][0][0])[i] = (f16)0.f;

  float cst = 0.f;

  const f16* gp = xg + ((size_t)(bb + q) * Tsz) * 512 + jcol * 4;

  floatx4 gacc[4];
  {
    f16x4 x0 = *(const f16x4*)gp;
#pragma unroll
    for (int g = 0; g < 4; ++g) {
      const float v = (float)x0[g];
      gacc[g][0] = v; gacc[g][1] = v; gacc[g][2] = v; gacc[g][3] = v;
    }
  }
  f16x4 s0 = *(const f16x4*)(gp + 512);
  f16x4 s1 = *(const f16x4*)(gp + 1024);
  const f16* gpn = gp + 3 * 512;

  __syncthreads();

  auto step = [&](int t, f16x4& sl) {
    f16x8 ah[4];
#pragma unroll
    for (int kt = 0; kt < 4; ++kt)
      ah[kt] = *(const f16x8*)(&hq[t & 1][hrow][kt * 32 + q * 8]);
#pragma unroll
    for (int kt = 0; kt < 4; ++kt)
#pragma unroll
      for (int g = 0; g < 4; ++g) gacc[g] = MFMA(ah[kt], wh[g][kt], gacc[g]);

    const float h = lstm_cell(gacc[0][0], gacc[1][0], gacc[2][0], gacc[3][0], cst);
    hq[(t + 1) & 1][q][jcol] = (f16)h;
    if (t == Tsz - 1)
      hfinal[(size_t)(bb + q) * Hsz + jcol] = h;

    if (t + 1 < Tsz) {
#pragma unroll
      for (int g = 0; g < 4; ++g) {
        const float v = (float)sl[g];
        gacc[g][0] = v; gacc[g][1] = v; gacc[g][2] = v; gacc[g][3] = v;
      }
      if (t + 3 < Tsz) { sl = *(const f16x4*)gpn; gpn += 512; }
    }
    lds_barrier();
  };

  for (int tb = 0; tb < Tsz; tb += 2) {
    step(tb + 0, s0);
    step(tb + 1, s1);
  }
}

// ---------------------------------------------------------------------------
// LEGACY PATH (smaller workspace): round-2 kernels, known-correct.
// ---------------------------------------------------------------------------

__global__ __launch_bounds__(256, 1) void lstm_scan_l0(
    const f16* __restrict__ xf,
    const float* __restrict__ Wih_f, const float* __restrict__ Whh_f,
    const float* __restrict__ bih_f, const float* __restrict__ bhh_f,
    const float* __restrict__ Wih_r, const float* __restrict__ Whh_r,
    const float* __restrict__ bih_r, const float* __restrict__ bhh_r,
    f16* __restrict__ hs) {
  const int dir = ((int)blockIdx.x >= 128) ? 1 : 0;
  const int bb = ((int)blockIdx.x & 127) * 2;
  const float* __restrict__ Wih = dir ? Wih_r : Wih_f;
  const float* __restrict__ Whh = dir ? Whh_r : Whh_f;
  const float* __restrict__ bih = dir ? bih_r : bih_f;
  const float* __restrict__ bhh = dir ? bhh_r : bhh_f;

  __shared__ __align__(16) f16 hq[2][2][160];

  const int tid = threadIdx.x;
  const int lane = tid & 63;
  const int w = tid >> 6;
  const int l15 = lane & 15;
  const int q = lane >> 4;
  const bool qb1 = (q & 2) != 0;
  const int mybat = q & 1;
  const int abat = (l15 >> 2) & 1;
  const int mycol = w * 32 + (qb1 ? 16 : 0) + l15;

  f16x8 wi[4][2][2], wh[4][2][4];
  float bsum[4][2];
#pragma unroll
  for (int g = 0; g < 4; ++g)
#pragma unroll
    for (int ct = 0; ct < 2; ++ct) {
      const int n = g * 128 + w * 32 + ct * 16 + l15;
#pragma unroll
      for (int kt = 0; kt < 2; ++kt) wi[g][ct][kt] = load_wfrag(Wih, n, Isz, kt * 32 + q * 8);
#pragma unroll
      for (int kt = 0; kt < 4; ++kt) wh[g][ct][kt] = load_wfrag(Whh, n, Hsz, kt * 32 + q * 8);
      bsum[g][ct] = bih[n] + bhh[n];
    }

  for (int i = tid; i < 2 * 2 * 160; i += 256) (&hq[0][0][0])[i] = (f16)0.f;

  float cst = 0.f;
  const int t0 = dir ? (Tsz - 1) : 0;
  const int dt = dir ? -1 : 1;
  const ptrdiff_t xstep = (ptrdiff_t)dt * Isz;

  const f16* xp = xf + ((size_t)(bb + abat) * Tsz + t0) * Isz + q * 8;

  floatx4 gacc[4][2];
  {
    f16x8 x0 = *(const f16x8*)xp;
    f16x8 x1 = *(const f16x8*)(xp + 32);
#pragma unroll
    for (int g = 0; g < 4; ++g)
#pragma unroll
      for (int ct = 0; ct < 2; ++ct) {
        floatx4 a;
        const float b = bsum[g][ct];
        a[0] = b; a[1] = b; a[2] = b; a[3] = b;
        a = MFMA(x0, wi[g][ct][0], a);
        a = MFMA(x1, wi[g][ct][1], a);
        gacc[g][ct] = a;
      }
  }

  f16x8 r0a = *(const f16x8*)(xp + 1 * xstep), r0b = *(const f16x8*)(xp + 1 * xstep + 32);
  f16x8 r1a = *(const f16x8*)(xp + 2 * xstep), r1b = *(const f16x8*)(xp + 2 * xstep + 32);
  const f16* xpn = xp + 3 * xstep;

  f16* hsp = hs + ((size_t)(bb + mybat) * Tsz + t0) * 256 + dir * 128 + mycol;
  const ptrdiff_t hstep = (ptrdiff_t)dt * 256;

  __syncthreads();

  auto step = [&](int t, f16x8& ra, f16x8& rb) {
    f16x8 ah[4];
#pragma unroll
    for (int kt = 0; kt < 4; ++kt)
      ah[kt] = *(const f16x8*)(&hq[t & 1][abat][kt * 32 + q * 8]);
#pragma unroll
    for (int kt = 0; kt < 4; ++kt)
#pragma unroll
      for (int g = 0; g < 4; ++g)
#pragma unroll
        for (int ct = 0; ct < 2; ++ct)
          gacc[g][ct] = MFMA(ah[kt], wh[g][ct][kt], gacc[g][ct]);

    const float ipre = qb1 ? gacc[0][1][0] : gacc[0][0][0];
    const float fpre = qb1 ? gacc[1][1][0] : gacc[1][0][0];
    const float gpre = qb1 ? gacc[2][1][0] : gacc[2][0][0];
    const float opre = qb1 ? gacc[3][1][0] : gacc[3][0][0];
    const float h = lstm_cell(ipre, fpre, gpre, opre, cst);
    const f16 hf = (f16)h;
    hq[(t + 1) & 1][mybat][mycol] = hf;
    *hsp = hf;
    hsp += hstep;

    if (t + 1 < Tsz) {
#pragma unroll
      for (int g = 0; g < 4; ++g)
#pragma unroll
        for (int ct = 0; ct < 2; ++ct) {
          floatx4 na;
          const float b = bsum[g][ct];
          na[0] = b; na[1] = b; na[2] = b; na[3] = b;
          na = MFMA(ra, wi[g][ct][0], na);
          na = MFMA(rb, wi[g][ct][1], na);
          gacc[g][ct] = na;
        }
      if (t + 3 < Tsz) {
        ra = *(const f16x8*)xpn;
        rb = *(const f16x8*)(xpn + 32);
        xpn += xstep;
      }
    }
    lds_barrier();
  };

  for (int tb = 0; tb < Tsz; tb += 2) {
    step(tb + 0, r0a, r0b);
    step(tb + 1, r1a, r1b);
  }
}

// xg GEMM for layer-1 fwd. Output layout: xg[b][t][col][g] f16x4 (biases
// folded). Grid 256 = 16 batch-groups x 16 t-chunks of 32.
__global__ __launch_bounds__(512, 1) void xg_gemm_l1(
    const f16* __restrict__ hs, const float* __restrict__ Wih,
    const float* __restrict__ bih, const float* __restrict__ bhh,
    f16* __restrict__ xg) {
  const int bg = (int)blockIdx.x & 15;
  const int tc = (int)blockIdx.x >> 4;
  const int bb = bg * 16;

  const int tid = threadIdx.x;
  const int lane = tid & 63;
  const int w = tid >> 6;
  const int l15 = lane & 15;
  const int q = lane >> 4;
  const int jcol = w * 16 + l15;

  f16x8 wi[4][8];
  floatx4 bvec[4];
#pragma unroll
  for (int g = 0; g < 4; ++g) {
    const int n = g * 128 + jcol;
#pragma unroll
    for (int kt = 0; kt < 8; ++kt) wi[g][kt] = load_wfrag(Wih, n, 256, kt * 32 + q * 8);
    const float b = bih[n] + bhh[n];
    bvec[g][0] = b; bvec[g][1] = b; bvec[g][2] = b; bvec[g][3] = b;
  }

  const f16* ap = hs + ((size_t)(bb + l15) * Tsz + tc * 32) * 256 + q * 8;
  f16* op = xg + (((size_t)(bb + 4 * q) * Tsz + tc * 32) * 128 + jcol) * 4;
  const size_t rstride = (size_t)Tsz * 512;

  for (int tt = 0; tt < 32; ++tt) {
    f16x8 a[8];
#pragma unroll
    for (int kt = 0; kt < 8; ++kt) a[kt] = *(const f16x8*)(ap + kt * 32);
    ap += 256;

    floatx4 acc[4];
#pragma unroll
    for (int g = 0; g < 4; ++g) acc[g] = MFMA(a[0], wi[g][0], bvec[g]);
#pragma unroll
    for (int kt = 1; kt < 8; ++kt)
#pragma unroll
      for (int g = 0; g < 4; ++g) acc[g] = MFMA(a[kt], wi[g][kt], acc[g]);

#pragma unroll
    for (int r = 0; r < 4; ++r) {
      f16x4 o;
      o[0] = (f16)acc[0][r]; o[1] = (f16)acc[1][r];
      o[2] = (f16)acc[2][r]; o[3] = (f16)acc[3][r];
      *(f16x4*)(op + (size_t)r * rstride) = o;
    }
    op += 512;
  }
}

// Legacy layer-1 scan (4-wave), kept for mid-tier workspace.
__global__ __launch_bounds__(256, 1) void lstm_scan_l1x(
    const f16* __restrict__ xg, const float* __restrict__ Whh,
    float* __restrict__ hfinal) {
  const int bb = (int)blockIdx.x * 2;

  __shared__ __align__(16) f16 hq[2][2][160];

  const int tid = threadIdx.x;
  const int lane = tid & 63;
  const int w = tid >> 6;
  const int l15 = lane & 15;
  const int q = lane >> 4;
  const bool qb1 = (q & 2) != 0;
  const int mybat = q & 1;
  const int abat = (l15 >> 2) & 1;
  const int mycol = w * 32 + (qb1 ? 16 : 0) + l15;

  f16x8 wh[4][2][4];
#pragma unroll
  for (int g = 0; g < 4; ++g)
#pragma unroll
    for (int ct = 0; ct < 2; ++ct) {
      const int n = g * 128 + w * 32 + ct * 16 + l15;
#pragma unroll
      for (int kt = 0; kt < 4; ++kt) wh[g][ct][kt] = load_wfrag(Whh, n, Hsz, kt * 32 + q * 8);
    }

  for (int i = tid; i < 2 * 2 * 160; i += 256) (&hq[0][0][0])[i] = (f16)0.f;

  float cst = 0.f;

  const f16* gp = xg + (size_t)(bb + mybat) * Tsz * 512 + (w * 32 + l15) * 4;
  f16x4 s0a = *(const f16x4*)gp,            s0b = *(const f16x4*)(gp + 64);
  f16x4 s1a = *(const f16x4*)(gp + 512),    s1b = *(const f16x4*)(gp + 576);
  f16x4 s2a = *(const f16x4*)(gp + 1024),   s2b = *(const f16x4*)(gp + 1088);
  f16x4 s3a = *(const f16x4*)(gp + 1536),   s3b = *(const f16x4*)(gp + 1600);
  const f16* gpn = gp + 2048;

  __syncthreads();

  auto step = [&](int t, f16x4& sa, f16x4& sb) {
    f16x8 ah[4];
#pragma unroll
    for (int kt = 0; kt < 4; ++kt)
      ah[kt] = *(const f16x8*)(&hq[t & 1][abat][kt * 32 + q * 8]);

    floatx4 gacc[4][2];
#pragma unroll
    for (int g = 0; g < 4; ++g) {
      const float v0 = (float)sa[g];
      const float v1 = (float)sb[g];
      gacc[g][0][0] = v0; gacc[g][0][1] = v0; gacc[g][0][2] = v0; gacc[g][0][3] = v0;
      gacc[g][1][0] = v1; gacc[g][1][1] = v1; gacc[g][1][2] = v1; gacc[g][1][3] = v1;
    }
#pragma unroll
    for (int kt = 0; kt < 4; ++kt)
#pragma unroll
      for (int g = 0; g < 4; ++g)
#pragma unroll
        for (int ct = 0; ct < 2; ++ct)
          gacc[g][ct] = MFMA(ah[kt], wh[g][ct][kt], gacc[g][ct]);

    const float ipre = qb1 ? gacc[0][1][0] : gacc[0][0][0];
    const float fpre = qb1 ? gacc[1][1][0] : gacc[1][0][0];
    const float gpre = qb1 ? gacc[2][1][0] : gacc[2][0][0];
    const float opre = qb1 ? gacc[3][1][0] : gacc[3][0][0];
    const float h = lstm_cell(ipre, fpre, gpre, opre, cst);
    hq[(t + 1) & 1][mybat][mycol] = (f16)h;
    if (t == Tsz - 1)
      hfinal[(size_t)(bb + mybat) * Hsz + mycol] = h;

    if (t + 4 < Tsz) {
      sa = *(const f16x4*)gpn;
      sb = *(const f16x4*)(gpn + 64);
      gpn += 512;
    }
    lds_barrier();
  };

  for (int tb = 0; tb < Tsz; tb += 4) {
    step(tb + 0, s0a, s0b);
    step(tb + 1, s1a, s1b);
    step(tb + 2, s2a, s2b);
    step(tb + 3, s3a, s3b);
  }
}

// Fallback layer-1 scan (reads hs directly) for small ws. 16 blocks.
__global__ __launch_bounds__(512, 1) void lstm_scan_l1_fb(
    const f16* __restrict__ hs,
    const float* __restrict__ Wih, const float* __restrict__ Whh,
    const float* __restrict__ bih, const float* __restrict__ bhh,
    float* __restrict__ hfinal) {
  const int bb = (int)blockIdx.x * 16;
  __shared__ __align__(16) f16 hq[2][16][136];
  __shared__ __align__(16) f16 xq[2][16][264];

  const int tid = threadIdx.x;
  const int lane = tid & 63;
  const int w = tid >> 6;
  const int l15 = lane & 15;
  const int q = lane >> 4;
  const int jcol = w * 16 + l15;

  f16x8 wi[4][8], wh[4][4];
  float bsum[4];
#pragma unroll
  for (int g = 0; g < 4; ++g) {
    const int n = g * 128 + jcol;
#pragma unroll
    for (int kt = 0; kt < 8; ++kt) wi[g][kt] = load_wfrag(Wih, n, 256, kt * 32 + q * 8);
#pragma unroll
    for (int kt = 0; kt < 4; ++kt) wh[g][kt] = load_wfrag(Whh, n, Hsz, kt * 32 + q * 8);
    bsum[g] = bih[n] + bhh[n];
  }
  for (int i = tid; i < 2 * 16 * 136; i += 512) (&hq[0][0][0])[i] = (f16)0.f;
  float cst[4] = {0.f, 0.f, 0.f, 0.f};

  floatx4 gacc[4];
  {
    const f16* pp = hs + (size_t)(bb + l15) * Tsz * 256 + q * 8;
#pragma unroll
    for (int g = 0; g < 4; ++g) {
      gacc[g][0] = bsum[g]; gacc[g][1] = bsum[g];
      gacc[g][2] = bsum[g]; gacc[g][3] = bsum[g];
    }
#pragma unroll
    for (int kt = 0; kt < 8; ++kt) {
      f16x8 xa = *(const f16x8*)(pp + kt * 32);
#pragma unroll
      for (int g = 0; g < 4; ++g) gacc[g] = MFMA(xa, wi[g][kt], gacc[g]);
    }
  }
  const int sm = tid >> 5;
  const int sc = tid & 31;
  const f16* spg = hs + (size_t)(bb + sm) * Tsz * 256 + sc * 8;
  const f16* spn = spg + 3 * 256;
  f16x8 ld;
  *(f16x8*)(&xq[1][sm][sc * 8]) = *(const f16x8*)(spg + 256);
  ld = *(const f16x8*)(spg + 2 * 256);
  __syncthreads();

  for (int t = 0; t < Tsz; ++t) {
    f16x8 xa[8];
    if (t + 1 < Tsz) {
      const f16* xrow = &xq[(t + 1) & 1][l15][0];
#pragma unroll
      for (int kt = 0; kt < 8; ++kt) xa[kt] = *(const f16x8*)(xrow + kt * 32 + q * 8);
    }
    f16x8 ah[4];
#pragma unroll
    for (int kt = 0; kt < 4; ++kt)
      ah[kt] = *(const f16x8*)(&hq[t & 1][l15][kt * 32 + q * 8]);
#pragma unroll
    for (int kt = 0; kt < 4; ++kt)
#pragma unroll
      for (int g = 0; g < 4; ++g) gacc[g] = MFMA(ah[kt], wh[g][kt], gacc[g]);

#pragma unroll
    for (int r = 0; r < 4; ++r) {
      const float h = lstm_cell(gacc[0][r], gacc[1][r], gacc[2][r], gacc[3][r], cst[r]);
      hq[(t + 1) & 1][4 * q + r][jcol] = (f16)h;
      if (t == Tsz - 1) hfinal[(size_t)(bb + 4 * q + r) * Hsz + jcol] = h;
    }
    if (t + 2 < Tsz) *(f16x8*)(&xq[t & 1][sm][sc * 8]) = ld;
    if (t + 3 < Tsz) { ld = *(const f16x8*)spn; spn += 256; }
    if (t + 1 < Tsz) {
      floatx4 nacc[4];
#pragma unroll
      for (int g = 0; g < 4; ++g) {
        nacc[g][0] = bsum[g]; nacc[g][1] = bsum[g];
        nacc[g][2] = bsum[g]; nacc[g][3] = bsum[g];
      }
#pragma unroll
      for (int kt = 0; kt < 8; ++kt)
#pragma unroll
        for (int g = 0; g < 4; ++g) nacc[g] = MFMA(xa[kt], wi[g][kt], nacc[g]);
#pragma unroll
      for (int g = 0; g < 4; ++g) gacc[g] = nacc[g];
    }
    lds_barrier();
  }
}

// L1-reverse single step (h0=c0=0) + FC head. 1 block/batch.
__global__ __launch_bounds__(512) void tail_kernel(
    const f16* __restrict__ hs, const float* __restrict__ hfinal,
    const float* __restrict__ Wr, const float* __restrict__ br1,
    const float* __restrict__ br2, const float* __restrict__ fc1w,
    const float* __restrict__ fc1b, const float* __restrict__ fc2w,
    const float* __restrict__ fc2b, float* __restrict__ out) {
  const int b = blockIdx.x;
  const int tid = threadIdx.x;
  __shared__ float hrow[256];
  __shared__ float gact[512];
  __shared__ float last[256];
  __shared__ float hid[128];
  __shared__ float psum[128];

  const size_t row = ((size_t)b * Tsz + (Tsz - 1)) * 256;
  if (tid < 256) hrow[tid] = (float)hs[row + tid];
  __syncthreads();

  {
    float a = br1[tid] + br2[tid];
    const float* wr = Wr + (size_t)tid * 256;
#pragma unroll 8
    for (int k = 0; k < 256; ++k) a += hrow[k] * wr[k];
    gact[tid] = (tid >= 256 && tid < 384) ? tanh_f(a) : sigm_f(a);
  }
  __syncthreads();

  if (tid < 128) {
    const float c = gact[tid] * gact[256 + tid];
    const float hb = gact[384 + tid] * tanh_f(c);
    last[tid] = hfinal[(size_t)b * Hsz + tid];
    last[128 + tid] = hb;
  }
  __syncthreads();

  if (tid < 128) {
    float a = fc1b[tid];
    const float* w1 = fc1w + (size_t)tid * 256;
#pragma unroll 8
    for (int k = 0; k < 256; ++k) a += last[k] * w1[k];
    hid[tid] = fmaxf(a, 0.f);
  }
  __syncthreads();
  if (tid < 128) psum[tid] = hid[tid] * fc2w[tid];
  __syncthreads();
  if (tid == 0) {
    float s = fc2b[0];
    for (int k = 0; k < 128; ++k) s += psum[k];
    out[b] = s;
  }
}

extern "C" void kernel_launch(void* const* d_in, const int* in_sizes, int n_in,
                              void* d_out, int out_size, void* d_ws, size_t ws_size,
                              hipStream_t stream) {
  (void)in_sizes; (void)n_in; (void)out_size;
  const float* x = (const float*)d_in[0];
  const float* Wih_l0 = (const float*)d_in[1];
  const float* Whh_l0 = (const float*)d_in[2];
  const float* bih_l0 = (const float*)d_in[3];
  const float* bhh_l0 = (const float*)d_in[4];
  const float* Wih_l0r = (const float*)d_in[5];
  const float* Whh_l0r = (const float*)d_in[6];
  const float* bih_l0r = (const float*)d_in[7];
  const float* bhh_l0r = (const float*)d_in[8];
  const float* Wih_l1 = (const float*)d_in[9];
  const float* Whh_l1 = (const float*)d_in[10];
  const float* bih_l1 = (const float*)d_in[11];
  const float* bhh_l1 = (const float*)d_in[12];
  const float* Wih_l1r = (const float*)d_in[13];
  // d_in[14] = W_hh_l1r unused (reverse h0 = 0)
  const float* bih_l1r = (const float*)d_in[15];
  const float* bhh_l1r = (const float*)d_in[16];
  const float* fc1w = (const float*)d_in[17];
  const float* fc1b = (const float*)d_in[18];
  const float* fc2w = (const float*)d_in[19];
  const float* fc2b = (const float*)d_in[20];
  float* out = (float*)d_out;

  char* ws = (char*)d_ws;
  const size_t M = (size_t)Bsz * Tsz;        // 131072
  const size_t XFB = M * Isz * 2;            // 16.8 MB  x in f16 (legacy)
  const size_t HSB = M * 256 * 2;            // 67.1 MB  hs in f16
  const size_t HFB = (size_t)Bsz * Hsz * 4;  // 131 KB   L1 fwd final h
  const size_t XGB = M * 512 * 2;            // 134 MB   one layer's xg f16
  const size_t XG0B = 2 * XGB;               // 268 MB   l0 xg, both dirs

  const size_t need_A = XG0B + HSB + HFB;          // ~336 MB  new path
  const size_t need_B = XFB + HSB + HFB + XGB;     // ~218 MB  legacy fast
  const size_t need_C = XFB + HSB + HFB;           // ~84 MB   fb

  if (ws_size >= need_A) {
    // new path: xg0 at 0; xg1 aliases xg0 (dead once scan_l0x finishes)
    f16* xg0 = (f16*)ws;
    f16* hsb = (f16*)(ws + XG0B);
    float* hfinal = (float*)(ws + XG0B + HSB);
    f16* xg1 = xg0;

    xg_gemm_l0<<<dim3(512), dim3(512), 0, stream>>>(
        x, Wih_l0, bih_l0, bhh_l0, Wih_l0r, bih_l0r, bhh_l0r, xg0);
    lstm_scan_l0x<<<dim3(128), dim3(512), 0, stream>>>(xg0, Whh_l0, Whh_l0r, hsb);
    xg_gemm_l1<<<dim3(256), dim3(512), 0, stream>>>(hsb, Wih_l1, bih_l1, bhh_l1, xg1);
    lstm_scan_l1y<<<dim3(64), dim3(512), 0, stream>>>(xg1, Whh_l1, hfinal);
    tail_kernel<<<dim3(256), dim3(512), 0, stream>>>(
        hsb, hfinal, Wih_l1r, bih_l1r, bhh_l1r, fc1w, fc1b, fc2w, fc2b, out);
    return;
  }

  if (ws_size < need_C) return;
  const bool fastB = ws_size >= need_B;

  size_t off = 0;
  f16* xf = (f16*)(ws + off); off += XFB;
  f16* hsb = (f16*)(ws + off); off += HSB;
  float* hfinal = (float*)(ws + off); off += HFB;
  f16* xgb = fastB ? (f16*)(ws + off) : nullptr;

  const int n4 = (int)(M * Isz / 4);
  cvt_f32_f16<<<dim3((n4 + 255) / 256), dim3(256), 0, stream>>>(x, xf, n4);

  lstm_scan_l0<<<dim3(256), dim3(256), 0, stream>>>(
      xf, Wih_l0, Whh_l0, bih_l0, bhh_l0, Wih_l0r, Whh_l0r, bih_l0r, bhh_l0r, hsb);

  if (fastB) {
    xg_gemm_l1<<<dim3(256), dim3(512), 0, stream>>>(hsb, Wih_l1, bih_l1, bhh_l1, xgb);
    lstm_scan_l1x<<<dim3(128), dim3(256), 0, stream>>>(xgb, Whh_l1, hfinal);
  } else {
    lstm_scan_l1_fb<<<dim3(16), dim3(512), 0, stream>>>(
        hsb, Wih_l1, Whh_l1, bih_l1, bhh_l1, hfinal);
  }

  tail_kernel<<<dim3(256), dim3(512), 0, stream>>>(
      hsb, hfinal, Wih_l1r, bih_l1r, bhh_l1r, fc1w, fc1b, fc2w, fc2b, out);
}